// Round 19
// baseline (677.708 us; speedup 1.0000x reference)
//
#include <hip/hip_runtime.h>
#include <cfloat>

#define NEG_SLOPE 0.2f

// ---------------- CSR build ----------------
__global__ __launch_bounds__(256) void zero_kernel(int* __restrict__ counts,
                                                   int* __restrict__ cursor, int n) {
    int gid = blockIdx.x * 256 + threadIdx.x;
    if (gid < n) { counts[gid] = 0; cursor[gid] = 0; }
}

__global__ __launch_bounds__(256) void count_kernel(const int* __restrict__ dst,
                                                    int* __restrict__ counts, int E) {
    int e = blockIdx.x * 256 + threadIdx.x;
    if (e < E) atomicAdd(&counts[dst[e]], 1);
}

// ---- hierarchical scan: 1024 elements per block ----
__global__ __launch_bounds__(256) void scan_bsums_kernel(const int* __restrict__ counts,
                                                         int* __restrict__ bsums, int N) {
    int t = threadIdx.x;
    int base = blockIdx.x * 1024 + t * 4;
    int s = 0;
    #pragma unroll
    for (int i = 0; i < 4; ++i) { int idx = base + i; if (idx < N) s += counts[idx]; }
    #pragma unroll
    for (int d = 1; d < 64; d <<= 1) s += __shfl_xor(s, d);
    __shared__ int ws[4];
    if ((t & 63) == 0) ws[t >> 6] = s;
    __syncthreads();
    if (t == 0) bsums[blockIdx.x] = ws[0] + ws[1] + ws[2] + ws[3];
}

__global__ __launch_bounds__(64) void scan_bscan_kernel(int* __restrict__ bsums, int NB) {
    int t = threadIdx.x;
    int v = (t < NB) ? bsums[t] : 0;
    int x = v;
    #pragma unroll
    for (int d = 1; d < 64; d <<= 1) {
        int y = __shfl_up(x, d);
        if (t >= d) x += y;
    }
    if (t < NB) bsums[t] = x - v;   // exclusive
}

__global__ __launch_bounds__(256) void scan_final_kernel(const int* __restrict__ counts,
                                                         const int* __restrict__ bsums,
                                                         int* __restrict__ offs, int N) {
    int t = threadIdx.x, lane = t & 63, w = t >> 6;
    int base = blockIdx.x * 1024 + t * 4;
    int v[4]; int s = 0;
    #pragma unroll
    for (int i = 0; i < 4; ++i) { int idx = base + i; v[i] = (idx < N) ? counts[idx] : 0; s += v[i]; }
    int x = s;
    #pragma unroll
    for (int d = 1; d < 64; d <<= 1) {
        int y = __shfl_up(x, d);
        if (lane >= d) x += y;
    }
    __shared__ int wtot[4];
    if (lane == 63) wtot[w] = x;
    __syncthreads();
    int wexc = 0;
    for (int i = 0; i < w; ++i) wexc += wtot[i];
    int run = (x - s) + wexc + bsums[blockIdx.x];
    #pragma unroll
    for (int i = 0; i < 4; ++i) {
        int idx = base + i;
        run += v[i];
        if (idx < N) offs[idx + 1] = run;
    }
    if (blockIdx.x == 0 && t == 0) offs[0] = 0;
}

// 4 edges per thread: 4 independent {read, atomic, write} chains -> 4x MLP
__global__ __launch_bounds__(256) void scatter_kernel(
    const int* __restrict__ src, const int* __restrict__ dst,
    const int* __restrict__ offs, int* __restrict__ cursor,
    int4* __restrict__ csr, int E) {
    int base = (blockIdx.x * 256 + threadIdx.x) * 4;
    if (base >= E) return;
    int n = E - base; if (n > 4) n = 4;
    int s0[4], d0[4], p0[4];
    #pragma unroll
    for (int i = 0; i < 4; ++i) {
        if (i < n) { s0[i] = src[base + i]; d0[i] = dst[base + i]; }
    }
    #pragma unroll
    for (int i = 0; i < 4; ++i) {
        if (i < n) p0[i] = offs[d0[i]] + atomicAdd(&cursor[d0[i]], 1);
    }
    #pragma unroll
    for (int i = 0; i < 4; ++i) {
        if (i < n) csr[p0[i]] = make_int4(s0[i], d0[i], base + i, 0);
    }
}

// canonical order: sort each dst-segment by eid (one wave per node, rank sort)
__global__ __launch_bounds__(256) void sort_segments_kernel(
    int4* __restrict__ csr, const int* __restrict__ offs, int N)
{
    int t = threadIdx.x;
    int lane = t & 63;
    int node = blockIdx.x * 4 + (t >> 6);
    if (node >= N) return;
    int off = offs[node];
    int deg = offs[node + 1] - off;
    if (deg <= 1) return;
    if (deg <= 64) {
        int key = 0x7FFFFFFF; int4 kv = make_int4(0, 0, 0, 0);
        if (lane < deg) { kv = csr[off + lane]; key = kv.z; }
        int rank = 0;
        #pragma unroll
        for (int i = 0; i < 64; ++i) {
            int ki = __shfl(key, i);
            if (ki < key) rank++;            // eids unique -> permutation
        }
        if (lane < deg) csr[off + rank] = kv;
    } else if (lane == 0) {
        for (int a = 1; a < deg; ++a) {
            int4 kv = csr[off + a];
            int b = a - 1;
            while (b >= 0 && csr[off + b].z > kv.z) {
                csr[off + b + 1] = csr[off + b];
                b--;
            }
            csr[off + b + 1] = kv;
        }
    }
}

// ---------------- per-layer kernels ----------------
// node_gemm v3: 64-row tile; lane=(row-slot, col-quad); LDS x broadcast + W float4.
#define XSTRIDE 68
__global__ __launch_bounds__(256) void node_gemm_kernel(
    const float* __restrict__ hin,
    const float* __restrict__ Wl, const float* __restrict__ bl,
    const float* __restrict__ Wr, const float* __restrict__ br,
    float* __restrict__ xl, float* __restrict__ xr, int nrows)
{
    __shared__ float sWl[4096];
    __shared__ float sWr[4096];
    __shared__ float sX[64 * XSTRIDE];
    int t = threadIdx.x;
    {
        float4* dl = (float4*)sWl; const float4* sl = (const float4*)Wl;
        float4* dr = (float4*)sWr; const float4* sr = (const float4*)Wr;
        for (int i = t; i < 1024; i += 256) { dl[i] = sl[i]; dr[i] = sr[i]; }
    }
    int row0 = blockIdx.x * 64;
    for (int i = t; i < 1024; i += 256) {
        int rr = i >> 4;
        int cc = (i & 15) << 2;
        int row = row0 + rr;
        float4 v = make_float4(0.f, 0.f, 0.f, 0.f);
        if (row < nrows) v = *(const float4*)(hin + (size_t)row * 64 + cc);
        *(float4*)(&sX[rr * XSTRIDE + cc]) = v;
    }
    __syncthreads();

    int lane = t & 63;
    int w = t >> 6;
    int rs = lane >> 4;
    int c4 = lane & 15;
    float4 bl4 = *(const float4*)(bl + c4 * 4);
    float4 br4 = *(const float4*)(br + c4 * 4);

    #pragma unroll
    for (int g = 0; g < 4; ++g) {
        int rloc = w * 16 + g * 4 + rs;
        int row = row0 + rloc;
        float4 al = {0.f, 0.f, 0.f, 0.f};
        float4 ar = {0.f, 0.f, 0.f, 0.f};
        const float* xrow = &sX[rloc * XSTRIDE];
        #pragma unroll 4
        for (int k = 0; k < 64; ++k) {
            float xk = xrow[k];
            float4 wl4 = *(const float4*)(&sWl[k * 64 + c4 * 4]);
            float4 wr4 = *(const float4*)(&sWr[k * 64 + c4 * 4]);
            al.x += xk * wl4.x; al.y += xk * wl4.y;
            al.z += xk * wl4.z; al.w += xk * wl4.w;
            ar.x += xk * wr4.x; ar.y += xk * wr4.y;
            ar.z += xk * wr4.z; ar.w += xk * wr4.w;
        }
        if (row < nrows) {
            float4 ol, orr;
            ol.x = al.x + bl4.x; ol.y = al.y + bl4.y;
            ol.z = al.z + bl4.z; ol.w = al.w + bl4.w;
            orr.x = ar.x + br4.x; orr.y = ar.y + br4.y;
            orr.z = ar.z + br4.z; orr.w = ar.w + br4.w;
            *(float4*)(xl + (size_t)row * 64 + c4 * 4) = ol;
            *(float4*)(xr + (size_t)row * 64 + c4 * 4) = orr;
        }
    }
}

// fused edge-score + aggregate: one WAVE per node.
// lane = (edge-slot eg 0..15, head h 0..3); 16 edges in flight per wave;
// each lane owns its head's 16 channels; per-slot online softmax; final
// 4-stage shfl_xor merge in fixed order (replay-deterministic).
__global__ __launch_bounds__(256) void fused_attn_kernel(
    const float* __restrict__ xl, const float* __restrict__ xr,
    const float* __restrict__ ea,
    const int4* __restrict__ csr, const int* __restrict__ offs,
    const float* __restrict__ We, const float* __restrict__ att,
    const float* __restrict__ bias, float* __restrict__ hout, int N)
{
    __shared__ float sWe[1024];   // 16 x 64
    __shared__ float sAtt[64];
    int t = threadIdx.x;
    ((float4*)sWe)[t] = ((const float4*)We)[t];          // 256 float4 = 1024 f
    if (t < 16) ((float4*)sAtt)[t] = ((const float4*)att)[t];
    __syncthreads();

    int lane = t & 63;
    int node = blockIdx.x * 4 + (t >> 6);
    if (node >= N) return;
    int eg = lane >> 2;      // edge slot 0..15
    int h  = lane & 3;       // head
    int hb = h * 16;         // channel base

    // node-uniform xr segment for my head (kept in regs)
    const float4* xrp = (const float4*)(xr + (size_t)node * 64 + hb);
    float4 r0 = xrp[0], r1 = xrp[1], r2 = xrp[2], r3 = xrp[3];

    int off = offs[node];
    int deg = offs[node + 1] - off;

    float m = -FLT_MAX, s = 0.f;
    float4 c0 = {0,0,0,0}, c1 = {0,0,0,0}, c2 = {0,0,0,0}, c3 = {0,0,0,0};

    for (int j0 = 0; j0 < deg; j0 += 16) {
        int j = j0 + eg;
        if (j < deg) {
            int4 se = csr[off + j];
            const float4* ap = (const float4*)(ea + (size_t)se.z * 16);
            float4 a0 = ap[0], a1 = ap[1], a2 = ap[2], a3 = ap[3];
            const float4* xp = (const float4*)(xl + (size_t)se.x * 64 + hb);
            float4 x0 = xp[0], x1 = xp[1], x2 = xp[2], x3 = xp[3];
            float av[16] = {a0.x, a0.y, a0.z, a0.w, a1.x, a1.y, a1.z, a1.w,
                            a2.x, a2.y, a2.z, a2.w, a3.x, a3.y, a3.z, a3.w};
            float4 e0 = {0,0,0,0}, e1 = {0,0,0,0}, e2 = {0,0,0,0}, e3 = {0,0,0,0};
            #pragma unroll
            for (int k = 0; k < 16; ++k) {
                float a = av[k];
                const float4* w4 = (const float4*)(&sWe[k * 64 + hb]);
                float4 w0 = w4[0], w1 = w4[1], w2 = w4[2], w3 = w4[3];
                e0.x += a * w0.x; e0.y += a * w0.y; e0.z += a * w0.z; e0.w += a * w0.w;
                e1.x += a * w1.x; e1.y += a * w1.y; e1.z += a * w1.z; e1.w += a * w1.w;
                e2.x += a * w2.x; e2.y += a * w2.y; e2.z += a * w2.z; e2.w += a * w2.w;
                e3.x += a * w3.x; e3.y += a * w3.y; e3.z += a * w3.z; e3.w += a * w3.w;
            }
            const float4* at4 = (const float4*)(&sAtt[hb]);
            float4 t0 = at4[0], t1 = at4[1], t2 = at4[2], t3 = at4[3];
            float sc = 0.f;
            {
                float q;
                q = x0.x + r0.x + e0.x; q = (q >= 0.f) ? q : NEG_SLOPE * q; sc += q * t0.x;
                q = x0.y + r0.y + e0.y; q = (q >= 0.f) ? q : NEG_SLOPE * q; sc += q * t0.y;
                q = x0.z + r0.z + e0.z; q = (q >= 0.f) ? q : NEG_SLOPE * q; sc += q * t0.z;
                q = x0.w + r0.w + e0.w; q = (q >= 0.f) ? q : NEG_SLOPE * q; sc += q * t0.w;
                q = x1.x + r1.x + e1.x; q = (q >= 0.f) ? q : NEG_SLOPE * q; sc += q * t1.x;
                q = x1.y + r1.y + e1.y; q = (q >= 0.f) ? q : NEG_SLOPE * q; sc += q * t1.y;
                q = x1.z + r1.z + e1.z; q = (q >= 0.f) ? q : NEG_SLOPE * q; sc += q * t1.z;
                q = x1.w + r1.w + e1.w; q = (q >= 0.f) ? q : NEG_SLOPE * q; sc += q * t1.w;
                q = x2.x + r2.x + e2.x; q = (q >= 0.f) ? q : NEG_SLOPE * q; sc += q * t2.x;
                q = x2.y + r2.y + e2.y; q = (q >= 0.f) ? q : NEG_SLOPE * q; sc += q * t2.y;
                q = x2.z + r2.z + e2.z; q = (q >= 0.f) ? q : NEG_SLOPE * q; sc += q * t2.z;
                q = x2.w + r2.w + e2.w; q = (q >= 0.f) ? q : NEG_SLOPE * q; sc += q * t2.w;
                q = x3.x + r3.x + e3.x; q = (q >= 0.f) ? q : NEG_SLOPE * q; sc += q * t3.x;
                q = x3.y + r3.y + e3.y; q = (q >= 0.f) ? q : NEG_SLOPE * q; sc += q * t3.y;
                q = x3.z + r3.z + e3.z; q = (q >= 0.f) ? q : NEG_SLOPE * q; sc += q * t3.z;
                q = x3.w + r3.w + e3.w; q = (q >= 0.f) ? q : NEG_SLOPE * q; sc += q * t3.w;
            }
            // online softmax update (per edge slot, serial in CSR order)
            float nm = fmaxf(m, sc);
            float cs = __expf(m - nm);        // 0 on first edge
            float p  = __expf(sc - nm);
            s = s * cs + p;
            c0.x = c0.x * cs + p * x0.x; c0.y = c0.y * cs + p * x0.y;
            c0.z = c0.z * cs + p * x0.z; c0.w = c0.w * cs + p * x0.w;
            c1.x = c1.x * cs + p * x1.x; c1.y = c1.y * cs + p * x1.y;
            c1.z = c1.z * cs + p * x1.z; c1.w = c1.w * cs + p * x1.w;
            c2.x = c2.x * cs + p * x2.x; c2.y = c2.y * cs + p * x2.y;
            c2.z = c2.z * cs + p * x2.z; c2.w = c2.w * cs + p * x2.w;
            c3.x = c3.x * cs + p * x3.x; c3.y = c3.y * cs + p * x3.y;
            c3.z = c3.z * cs + p * x3.z; c3.w = c3.w * cs + p * x3.w;
            m = nm;
        }
    }

    // merge the 16 edge-slot states (fixed xor order -> deterministic)
    #pragma unroll
    for (int st = 4; st < 64; st <<= 1) {
        float mo = __shfl_xor(m, st);
        float so = __shfl_xor(s, st);
        float4 o0, o1, o2, o3;
        o0.x = __shfl_xor(c0.x, st); o0.y = __shfl_xor(c0.y, st);
        o0.z = __shfl_xor(c0.z, st); o0.w = __shfl_xor(c0.w, st);
        o1.x = __shfl_xor(c1.x, st); o1.y = __shfl_xor(c1.y, st);
        o1.z = __shfl_xor(c1.z, st); o1.w = __shfl_xor(c1.w, st);
        o2.x = __shfl_xor(c2.x, st); o2.y = __shfl_xor(c2.y, st);
        o2.z = __shfl_xor(c2.z, st); o2.w = __shfl_xor(c2.w, st);
        o3.x = __shfl_xor(c3.x, st); o3.y = __shfl_xor(c3.y, st);
        o3.z = __shfl_xor(c3.z, st); o3.w = __shfl_xor(c3.w, st);
        float nm = fmaxf(m, mo);
        float cs = __expf(m - nm);
        float co = __expf(mo - nm);
        s = s * cs + so * co;
        c0.x = c0.x * cs + o0.x * co; c0.y = c0.y * cs + o0.y * co;
        c0.z = c0.z * cs + o0.z * co; c0.w = c0.w * cs + o0.w * co;
        c1.x = c1.x * cs + o1.x * co; c1.y = c1.y * cs + o1.y * co;
        c1.z = c1.z * cs + o1.z * co; c1.w = c1.w * cs + o1.w * co;
        c2.x = c2.x * cs + o2.x * co; c2.y = c2.y * cs + o2.y * co;
        c2.z = c2.z * cs + o2.z * co; c2.w = c2.w * cs + o2.w * co;
        c3.x = c3.x * cs + o3.x * co; c3.y = c3.y * cs + o3.y * co;
        c3.z = c3.z * cs + o3.z * co; c3.w = c3.w * cs + o3.w * co;
        m = nm;
    }

    if (eg == 0) {
        float inv = (deg > 0) ? 1.f / s : 0.f;
        const float4* bp = (const float4*)(bias + hb);
        float4 b0 = bp[0], b1 = bp[1], b2 = bp[2], b3 = bp[3];
        float4 o;
        float* orow = hout + (size_t)node * 64 + hb;
        o.x = fmaxf(c0.x * inv + b0.x, 0.f); o.y = fmaxf(c0.y * inv + b0.y, 0.f);
        o.z = fmaxf(c0.z * inv + b0.z, 0.f); o.w = fmaxf(c0.w * inv + b0.w, 0.f);
        ((float4*)orow)[0] = o;
        o.x = fmaxf(c1.x * inv + b1.x, 0.f); o.y = fmaxf(c1.y * inv + b1.y, 0.f);
        o.z = fmaxf(c1.z * inv + b1.z, 0.f); o.w = fmaxf(c1.w * inv + b1.w, 0.f);
        ((float4*)orow)[1] = o;
        o.x = fmaxf(c2.x * inv + b2.x, 0.f); o.y = fmaxf(c2.y * inv + b2.y, 0.f);
        o.z = fmaxf(c2.z * inv + b2.z, 0.f); o.w = fmaxf(c2.w * inv + b2.w, 0.f);
        ((float4*)orow)[2] = o;
        o.x = fmaxf(c3.x * inv + b3.x, 0.f); o.y = fmaxf(c3.y * inv + b3.y, 0.f);
        o.z = fmaxf(c3.z * inv + b3.z, 0.f); o.w = fmaxf(c3.w * inv + b3.w, 0.f);
        ((float4*)orow)[3] = o;
    }
}

extern "C" void kernel_launch(void* const* d_in, const int* in_sizes, int n_in,
                              void* d_out, int out_size, void* d_ws, size_t ws_size,
                              hipStream_t stream) {
    const float* x    = (const float*)d_in[0];
    const int*   eidx = (const int*)d_in[1];
    const float* ea   = (const float*)d_in[2];
    const float* Wl   = (const float*)d_in[3];
    const float* bl   = (const float*)d_in[4];
    const float* Wr   = (const float*)d_in[5];
    const float* br   = (const float*)d_in[6];
    const float* We   = (const float*)d_in[7];
    const float* att  = (const float*)d_in[8];
    const float* bias = (const float*)d_in[9];
    float* out = (float*)d_out;

    const int N = in_sizes[0] / 64;
    const int E = in_sizes[1] / 2;
    const int* src = eidx;
    const int* dst = eidx + E;

    float* ws = (float*)d_ws;
    float* xl      = ws;                               // N*64
    float* xr      = xl + (size_t)N * 64;              // N*64
    float* h_tmp   = xr + (size_t)N * 64;              // N*64
    int* counts    = (int*)(h_tmp + (size_t)N * 64);   // N
    int* cursor    = counts + N;                       // N
    int* offs      = cursor + N;                       // N+1
    int* bsums     = offs + N + 1;                     // 64
    uintptr_t p    = (uintptr_t)(bsums + 64);
    p = (p + 15) & ~(uintptr_t)15;
    int4* csr      = (int4*)p;                         // E int4 (16B aligned)

    dim3 blk(256);
    int g_n    = (N + 255) / 256;
    int g_e    = (E + 255) / 256;
    int g_e4   = (E + 1023) / 1024;
    int g_gemm = (N + 63) / 64;
    int g_node = (N + 3) / 4;
    int NB     = (N + 1023) / 1024;   // 49 for N=50000 (<= 64)

    // CSR over dst, canonical eid order (edge_index is layer-invariant)
    zero_kernel<<<g_n, blk, 0, stream>>>(counts, cursor, N);
    count_kernel<<<g_e, blk, 0, stream>>>(dst, counts, E);
    scan_bsums_kernel<<<NB, blk, 0, stream>>>(counts, bsums, N);
    scan_bscan_kernel<<<1, 64, 0, stream>>>(bsums, NB);
    scan_final_kernel<<<NB, blk, 0, stream>>>(counts, bsums, offs, N);
    scatter_kernel<<<g_e4, blk, 0, stream>>>(src, dst, offs, cursor, csr, E);
    sort_segments_kernel<<<g_node, blk, 0, stream>>>(csr, offs, N);

    const float* hin = x;
    for (int l = 0; l < 3; ++l) {
        float* hout = (l == 2) ? out : h_tmp;
        node_gemm_kernel<<<g_gemm, blk, 0, stream>>>(hin, Wl + (size_t)l * 4096, bl + l * 64,
                                                     Wr + (size_t)l * 4096, br + l * 64, xl, xr, N);
        fused_attn_kernel<<<g_node, blk, 0, stream>>>(xl, xr, ea, csr, offs,
                                                      We + (size_t)l * 1024, att + l * 64,
                                                      bias + l * 64, hout, N);
        hin = hout;
    }
}

// Round 20
// 494.647 us; speedup vs baseline: 1.3701x; 1.3701x over previous
//
#include <hip/hip_runtime.h>
#include <cfloat>

#define NEG_SLOPE 0.2f

// ---------------- CSR build ----------------
__global__ __launch_bounds__(256) void zero_kernel(int* __restrict__ counts,
                                                   int* __restrict__ cursor, int n) {
    int gid = blockIdx.x * 256 + threadIdx.x;
    if (gid < n) { counts[gid] = 0; cursor[gid] = 0; }
}

__global__ __launch_bounds__(256) void count_kernel(const int* __restrict__ dst,
                                                    int* __restrict__ counts, int E) {
    int e = blockIdx.x * 256 + threadIdx.x;
    if (e < E) atomicAdd(&counts[dst[e]], 1);
}

// ---- hierarchical scan: 1024 elements per block ----
__global__ __launch_bounds__(256) void scan_bsums_kernel(const int* __restrict__ counts,
                                                         int* __restrict__ bsums, int N) {
    int t = threadIdx.x;
    int base = blockIdx.x * 1024 + t * 4;
    int s = 0;
    #pragma unroll
    for (int i = 0; i < 4; ++i) { int idx = base + i; if (idx < N) s += counts[idx]; }
    #pragma unroll
    for (int d = 1; d < 64; d <<= 1) s += __shfl_xor(s, d);
    __shared__ int ws[4];
    if ((t & 63) == 0) ws[t >> 6] = s;
    __syncthreads();
    if (t == 0) bsums[blockIdx.x] = ws[0] + ws[1] + ws[2] + ws[3];
}

__global__ __launch_bounds__(64) void scan_bscan_kernel(int* __restrict__ bsums, int NB) {
    int t = threadIdx.x;
    int v = (t < NB) ? bsums[t] : 0;
    int x = v;
    #pragma unroll
    for (int d = 1; d < 64; d <<= 1) {
        int y = __shfl_up(x, d);
        if (t >= d) x += y;
    }
    if (t < NB) bsums[t] = x - v;   // exclusive
}

__global__ __launch_bounds__(256) void scan_final_kernel(const int* __restrict__ counts,
                                                         const int* __restrict__ bsums,
                                                         int* __restrict__ offs, int N) {
    int t = threadIdx.x, lane = t & 63, w = t >> 6;
    int base = blockIdx.x * 1024 + t * 4;
    int v[4]; int s = 0;
    #pragma unroll
    for (int i = 0; i < 4; ++i) { int idx = base + i; v[i] = (idx < N) ? counts[idx] : 0; s += v[i]; }
    int x = s;
    #pragma unroll
    for (int d = 1; d < 64; d <<= 1) {
        int y = __shfl_up(x, d);
        if (lane >= d) x += y;
    }
    __shared__ int wtot[4];
    if (lane == 63) wtot[w] = x;
    __syncthreads();
    int wexc = 0;
    for (int i = 0; i < w; ++i) wexc += wtot[i];
    int run = (x - s) + wexc + bsums[blockIdx.x];
    #pragma unroll
    for (int i = 0; i < 4; ++i) {
        int idx = base + i;
        run += v[i];
        if (idx < N) offs[idx + 1] = run;
    }
    if (blockIdx.x == 0 && t == 0) offs[0] = 0;
}

// 8 edges per thread: 8 independent {read, atomic, write} chains -> 8x MLP
__global__ __launch_bounds__(256) void scatter_kernel(
    const int* __restrict__ src, const int* __restrict__ dst,
    const int* __restrict__ offs, int* __restrict__ cursor,
    int4* __restrict__ csr, int E) {
    int base = (blockIdx.x * 256 + threadIdx.x) * 8;
    if (base >= E) return;
    int n = E - base; if (n > 8) n = 8;
    int s0[8], d0[8], p0[8];
    #pragma unroll
    for (int i = 0; i < 8; ++i) {
        if (i < n) { s0[i] = src[base + i]; d0[i] = dst[base + i]; }
    }
    #pragma unroll
    for (int i = 0; i < 8; ++i) {
        if (i < n) p0[i] = offs[d0[i]] + atomicAdd(&cursor[d0[i]], 1);
    }
    #pragma unroll
    for (int i = 0; i < 8; ++i) {
        if (i < n) csr[p0[i]] = make_int4(s0[i], d0[i], base + i, 0);
    }
}

// canonical order: sort each dst-segment by eid (one wave per node, rank sort)
__global__ __launch_bounds__(256) void sort_segments_kernel(
    int4* __restrict__ csr, const int* __restrict__ offs, int N)
{
    int t = threadIdx.x;
    int lane = t & 63;
    int node = blockIdx.x * 4 + (t >> 6);
    if (node >= N) return;
    int off = offs[node];
    int deg = offs[node + 1] - off;
    if (deg <= 1) return;
    if (deg <= 64) {
        int key = 0x7FFFFFFF; int4 kv = make_int4(0, 0, 0, 0);
        if (lane < deg) { kv = csr[off + lane]; key = kv.z; }
        int rank = 0;
        #pragma unroll
        for (int i = 0; i < 64; ++i) {
            int ki = __shfl(key, i);
            if (ki < key) rank++;            // eids unique -> permutation
        }
        if (lane < deg) csr[off + rank] = kv;
    } else if (lane == 0) {
        for (int a = 1; a < deg; ++a) {
            int4 kv = csr[off + a];
            int b = a - 1;
            while (b >= 0 && csr[off + b].z > kv.z) {
                csr[off + b + 1] = csr[off + b];
                b--;
            }
            csr[off + b + 1] = kv;
        }
    }
}

// ---------------- per-layer kernels ----------------
// node_gemm v4: 64-row tile; 4 rows per lane share each W read.
// Per k: 2 ds_read_b128 (W) + 4 b32 (x broadcast) feed 32 FMAs.
#define XSTRIDE 68
__global__ __launch_bounds__(256) void node_gemm_kernel(
    const float* __restrict__ hin,
    const float* __restrict__ Wl, const float* __restrict__ bl,
    const float* __restrict__ Wr, const float* __restrict__ br,
    float* __restrict__ xl, float* __restrict__ xr, int nrows)
{
    __shared__ float sWl[4096];
    __shared__ float sWr[4096];
    __shared__ float sX[64 * XSTRIDE];
    int t = threadIdx.x;
    {
        float4* dl = (float4*)sWl; const float4* sl = (const float4*)Wl;
        float4* dr = (float4*)sWr; const float4* sr = (const float4*)Wr;
        for (int i = t; i < 1024; i += 256) { dl[i] = sl[i]; dr[i] = sr[i]; }
    }
    int row0 = blockIdx.x * 64;
    for (int i = t; i < 1024; i += 256) {
        int rr = i >> 4;
        int cc = (i & 15) << 2;
        int row = row0 + rr;
        float4 v = make_float4(0.f, 0.f, 0.f, 0.f);
        if (row < nrows) v = *(const float4*)(hin + (size_t)row * 64 + cc);
        *(float4*)(&sX[rr * XSTRIDE + cc]) = v;
    }
    __syncthreads();

    int lane = t & 63;
    int w = t >> 6;
    int rs = lane >> 4;          // row slot 0..3
    int c4 = lane & 15;          // column quad
    int rbase = w * 16 + rs * 4; // 4 consecutive rows per lane

    float4 al0 = {0,0,0,0}, al1 = {0,0,0,0}, al2 = {0,0,0,0}, al3 = {0,0,0,0};
    float4 ar0 = {0,0,0,0}, ar1 = {0,0,0,0}, ar2 = {0,0,0,0}, ar3 = {0,0,0,0};
    const float* x0p = &sX[(rbase + 0) * XSTRIDE];
    const float* x1p = &sX[(rbase + 1) * XSTRIDE];
    const float* x2p = &sX[(rbase + 2) * XSTRIDE];
    const float* x3p = &sX[(rbase + 3) * XSTRIDE];

    #pragma unroll 4
    for (int k = 0; k < 64; ++k) {
        float4 wl4 = *(const float4*)(&sWl[k * 64 + c4 * 4]);
        float4 wr4 = *(const float4*)(&sWr[k * 64 + c4 * 4]);
        float xk0 = x0p[k], xk1 = x1p[k], xk2 = x2p[k], xk3 = x3p[k];
        al0.x += xk0 * wl4.x; al0.y += xk0 * wl4.y; al0.z += xk0 * wl4.z; al0.w += xk0 * wl4.w;
        al1.x += xk1 * wl4.x; al1.y += xk1 * wl4.y; al1.z += xk1 * wl4.z; al1.w += xk1 * wl4.w;
        al2.x += xk2 * wl4.x; al2.y += xk2 * wl4.y; al2.z += xk2 * wl4.z; al2.w += xk2 * wl4.w;
        al3.x += xk3 * wl4.x; al3.y += xk3 * wl4.y; al3.z += xk3 * wl4.z; al3.w += xk3 * wl4.w;
        ar0.x += xk0 * wr4.x; ar0.y += xk0 * wr4.y; ar0.z += xk0 * wr4.z; ar0.w += xk0 * wr4.w;
        ar1.x += xk1 * wr4.x; ar1.y += xk1 * wr4.y; ar1.z += xk1 * wr4.z; ar1.w += xk1 * wr4.w;
        ar2.x += xk2 * wr4.x; ar2.y += xk2 * wr4.y; ar2.z += xk2 * wr4.z; ar2.w += xk2 * wr4.w;
        ar3.x += xk3 * wr4.x; ar3.y += xk3 * wr4.y; ar3.z += xk3 * wr4.z; ar3.w += xk3 * wr4.w;
    }

    float4 bl4 = *(const float4*)(bl + c4 * 4);
    float4 br4 = *(const float4*)(br + c4 * 4);
    #pragma unroll
    for (int r = 0; r < 4; ++r) {
        int row = row0 + rbase + r;
        if (row >= nrows) break;
        float4 av = (r == 0) ? al0 : (r == 1) ? al1 : (r == 2) ? al2 : al3;
        float4 bv = (r == 0) ? ar0 : (r == 1) ? ar1 : (r == 2) ? ar2 : ar3;
        float4 ol, orr;
        ol.x = av.x + bl4.x; ol.y = av.y + bl4.y; ol.z = av.z + bl4.z; ol.w = av.w + bl4.w;
        orr.x = bv.x + br4.x; orr.y = bv.y + br4.y; orr.z = bv.z + br4.z; orr.w = bv.w + br4.w;
        *(float4*)(xl + (size_t)row * 64 + c4 * 4) = ol;
        *(float4*)(xr + (size_t)row * 64 + c4 * 4) = orr;
    }
}

// one thread per (CSR position, head); We read as float4 (ds_read_b128)
__global__ __launch_bounds__(256) void edge_score_kernel(
    const float* __restrict__ xl, const float* __restrict__ xr,
    const float* __restrict__ ea,
    const int4* __restrict__ csr,
    const float* __restrict__ We, const float* __restrict__ att,
    float* __restrict__ score_csr, int E)
{
    __shared__ float sWe[1024];   // 16 x 64
    __shared__ float sAtt[64];    // 4 x 16
    int t = threadIdx.x;
    for (int i = t; i < 1024; i += 256) sWe[i] = We[i];
    if (t < 64) sAtt[t] = att[t];
    __syncthreads();
    int gid = blockIdx.x * 256 + t;
    int pos = gid >> 2, h = gid & 3;
    if (pos >= E) return;
    int4 se = csr[pos];
    int s = se.x, d = se.y;
    const float4* eap = (const float4*)(ea + (size_t)se.z * 16);
    float4 a0 = eap[0], a1 = eap[1], a2 = eap[2], a3 = eap[3];
    float av[16] = {a0.x, a0.y, a0.z, a0.w, a1.x, a1.y, a1.z, a1.w,
                    a2.x, a2.y, a2.z, a2.w, a3.x, a3.y, a3.z, a3.w};
    const float4* xls = (const float4*)(xl + (size_t)s * 64 + h * 16);
    const float4* xrd = (const float4*)(xr + (size_t)d * 64 + h * 16);
    float4 vl0 = xls[0], vl1 = xls[1], vl2 = xls[2], vl3 = xls[3];
    float4 vr0 = xrd[0], vr1 = xrd[1], vr2 = xrd[2], vr3 = xrd[3];

    float4 ef0 = {0.f,0.f,0.f,0.f}, ef1 = {0.f,0.f,0.f,0.f};
    float4 ef2 = {0.f,0.f,0.f,0.f}, ef3 = {0.f,0.f,0.f,0.f};
    #pragma unroll
    for (int k = 0; k < 16; ++k) {
        float a = av[k];
        const float4* w4 = (const float4*)(&sWe[k * 64 + h * 16]);
        float4 w0 = w4[0], w1 = w4[1], w2 = w4[2], w3 = w4[3];
        ef0.x += a * w0.x; ef0.y += a * w0.y; ef0.z += a * w0.z; ef0.w += a * w0.w;
        ef1.x += a * w1.x; ef1.y += a * w1.y; ef1.z += a * w1.z; ef1.w += a * w1.w;
        ef2.x += a * w2.x; ef2.y += a * w2.y; ef2.z += a * w2.z; ef2.w += a * w2.w;
        ef3.x += a * w3.x; ef3.y += a * w3.y; ef3.z += a * w3.z; ef3.w += a * w3.w;
    }

    const float4* at4 = (const float4*)(&sAtt[h * 16]);
    float4 at0 = at4[0], at1 = at4[1], at2 = at4[2], at3 = at4[3];

    float sc0 = 0.f, sc1 = 0.f, sc2 = 0.f, sc3 = 0.f;
    {
        float m0 = vl0.x + vr0.x + ef0.x; m0 = (m0 >= 0.f) ? m0 : NEG_SLOPE * m0;
        float m1 = vl0.y + vr0.y + ef0.y; m1 = (m1 >= 0.f) ? m1 : NEG_SLOPE * m1;
        float m2 = vl0.z + vr0.z + ef0.z; m2 = (m2 >= 0.f) ? m2 : NEG_SLOPE * m2;
        float m3 = vl0.w + vr0.w + ef0.w; m3 = (m3 >= 0.f) ? m3 : NEG_SLOPE * m3;
        sc0 += m0 * at0.x; sc1 += m1 * at0.y; sc2 += m2 * at0.z; sc3 += m3 * at0.w;
    }
    {
        float m0 = vl1.x + vr1.x + ef1.x; m0 = (m0 >= 0.f) ? m0 : NEG_SLOPE * m0;
        float m1 = vl1.y + vr1.y + ef1.y; m1 = (m1 >= 0.f) ? m1 : NEG_SLOPE * m1;
        float m2 = vl1.z + vr1.z + ef1.z; m2 = (m2 >= 0.f) ? m2 : NEG_SLOPE * m2;
        float m3 = vl1.w + vr1.w + ef1.w; m3 = (m3 >= 0.f) ? m3 : NEG_SLOPE * m3;
        sc0 += m0 * at1.x; sc1 += m1 * at1.y; sc2 += m2 * at1.z; sc3 += m3 * at1.w;
    }
    {
        float m0 = vl2.x + vr2.x + ef2.x; m0 = (m0 >= 0.f) ? m0 : NEG_SLOPE * m0;
        float m1 = vl2.y + vr2.y + ef2.y; m1 = (m1 >= 0.f) ? m1 : NEG_SLOPE * m1;
        float m2 = vl2.z + vr2.z + ef2.z; m2 = (m2 >= 0.f) ? m2 : NEG_SLOPE * m2;
        float m3 = vl2.w + vr2.w + ef2.w; m3 = (m3 >= 0.f) ? m3 : NEG_SLOPE * m3;
        sc0 += m0 * at2.x; sc1 += m1 * at2.y; sc2 += m2 * at2.z; sc3 += m3 * at2.w;
    }
    {
        float m0 = vl3.x + vr3.x + ef3.x; m0 = (m0 >= 0.f) ? m0 : NEG_SLOPE * m0;
        float m1 = vl3.y + vr3.y + ef3.y; m1 = (m1 >= 0.f) ? m1 : NEG_SLOPE * m1;
        float m2 = vl3.z + vr3.z + ef3.z; m2 = (m2 >= 0.f) ? m2 : NEG_SLOPE * m2;
        float m3 = vl3.w + vr3.w + ef3.w; m3 = (m3 >= 0.f) ? m3 : NEG_SLOPE * m3;
        sc0 += m0 * at3.x; sc1 += m1 * at3.y; sc2 += m2 * at3.z; sc3 += m3 * at3.w;
    }
    score_csr[gid] = (sc0 + sc1) + (sc2 + sc3);
}

// one WAVE per node; lane = (edge-slot eg 0..3, channel-quad k 0..15, head = k>>2)
__global__ __launch_bounds__(256) void node_pass_kernel(
    const float* __restrict__ score_csr, const float* __restrict__ xl,
    const int4* __restrict__ csr,
    const int* __restrict__ offs, const float* __restrict__ bias,
    float* __restrict__ hout, int N)
{
    int t = threadIdx.x;
    int lane = t & 63;
    int node = blockIdx.x * 4 + (t >> 6);
    if (node >= N) return;
    int eg = lane >> 4;          // edge slot
    int k  = lane & 15;          // channel quad; head = k>>2
    int h  = k >> 2;
    int off = offs[node];
    int deg = offs[node + 1] - off;

    if (deg == 0) {
        if (eg == 0) {
            float4 b = *(const float4*)(bias + k * 4);
            float4 o;
            o.x = fmaxf(b.x, 0.f); o.y = fmaxf(b.y, 0.f);
            o.z = fmaxf(b.z, 0.f); o.w = fmaxf(b.w, 0.f);
            *(float4*)(hout + (size_t)node * 64 + k * 4) = o;
        }
        return;
    }

    // pass 1: head max (exact, order-free)
    float mx = -FLT_MAX;
    for (int j0 = 0; j0 < deg; j0 += 4) {
        int j = j0 + eg;
        if (j < deg) {
            float sc = score_csr[(size_t)(off + j) * 4 + h];
            mx = fmaxf(mx, sc);
        }
    }
    mx = fmaxf(mx, __shfl_xor(mx, 16));
    mx = fmaxf(mx, __shfl_xor(mx, 32));

    // pass 2: 4 edges per iteration, float4 FMA payload
    float4 acc = {0.f, 0.f, 0.f, 0.f};
    float sSum = 0.f;
    for (int j0 = 0; j0 < deg; j0 += 4) {
        int j = j0 + eg;
        int jj = (j < deg) ? j : deg - 1;
        int pos = off + jj;
        int s = csr[pos].x;
        float sc = score_csr[(size_t)pos * 4 + h];
        float ex = (j < deg) ? __expf(sc - mx) : 0.f;
        float4 v = *(const float4*)(xl + (size_t)s * 64 + k * 4);
        acc.x += ex * v.x; acc.y += ex * v.y;
        acc.z += ex * v.z; acc.w += ex * v.w;
        sSum += ex;
    }

    // fixed-grouping butterfly reduce (deterministic)
    acc.x += __shfl_xor(acc.x, 16); acc.y += __shfl_xor(acc.y, 16);
    acc.z += __shfl_xor(acc.z, 16); acc.w += __shfl_xor(acc.w, 16);
    sSum  += __shfl_xor(sSum, 16);
    acc.x += __shfl_xor(acc.x, 32); acc.y += __shfl_xor(acc.y, 32);
    acc.z += __shfl_xor(acc.z, 32); acc.w += __shfl_xor(acc.w, 32);
    sSum  += __shfl_xor(sSum, 32);

    if (eg == 0) {
        float inv = 1.f / sSum;
        float4 b = *(const float4*)(bias + k * 4);
        float4 o;
        o.x = fmaxf(acc.x * inv + b.x, 0.f);
        o.y = fmaxf(acc.y * inv + b.y, 0.f);
        o.z = fmaxf(acc.z * inv + b.z, 0.f);
        o.w = fmaxf(acc.w * inv + b.w, 0.f);
        *(float4*)(hout + (size_t)node * 64 + k * 4) = o;
    }
}

extern "C" void kernel_launch(void* const* d_in, const int* in_sizes, int n_in,
                              void* d_out, int out_size, void* d_ws, size_t ws_size,
                              hipStream_t stream) {
    const float* x    = (const float*)d_in[0];
    const int*   eidx = (const int*)d_in[1];
    const float* ea   = (const float*)d_in[2];
    const float* Wl   = (const float*)d_in[3];
    const float* bl   = (const float*)d_in[4];
    const float* Wr   = (const float*)d_in[5];
    const float* br   = (const float*)d_in[6];
    const float* We   = (const float*)d_in[7];
    const float* att  = (const float*)d_in[8];
    const float* bias = (const float*)d_in[9];
    float* out = (float*)d_out;

    const int N = in_sizes[0] / 64;
    const int E = in_sizes[1] / 2;
    const int* src = eidx;
    const int* dst = eidx + E;

    float* ws = (float*)d_ws;
    float* xl      = ws;                               // N*64
    float* xr      = xl + (size_t)N * 64;              // N*64
    float* score   = xr + (size_t)N * 64;              // E*4
    float* h_tmp   = score + (size_t)E * 4;            // N*64
    int* counts    = (int*)(h_tmp + (size_t)N * 64);   // N
    int* cursor    = counts + N;                       // N
    int* offs      = cursor + N;                       // N+1
    int* bsums     = offs + N + 1;                     // 64
    uintptr_t p    = (uintptr_t)(bsums + 64);
    p = (p + 15) & ~(uintptr_t)15;
    int4* csr      = (int4*)p;                         // E int4 (16B aligned)

    dim3 blk(256);
    int g_n    = (N + 255) / 256;
    int g_e    = (E + 255) / 256;
    int g_e8   = (E + 2047) / 2048;
    int g_eh   = (E * 4 + 255) / 256;
    int g_gemm = (N + 63) / 64;
    int g_node = (N + 3) / 4;
    int NB     = (N + 1023) / 1024;   // 49 for N=50000 (<= 64)

    // CSR over dst, canonical eid order (edge_index is layer-invariant)
    zero_kernel<<<g_n, blk, 0, stream>>>(counts, cursor, N);
    count_kernel<<<g_e, blk, 0, stream>>>(dst, counts, E);
    scan_bsums_kernel<<<NB, blk, 0, stream>>>(counts, bsums, N);
    scan_bscan_kernel<<<1, 64, 0, stream>>>(bsums, NB);
    scan_final_kernel<<<NB, blk, 0, stream>>>(counts, bsums, offs, N);
    scatter_kernel<<<g_e8, blk, 0, stream>>>(src, dst, offs, cursor, csr, E);
    sort_segments_kernel<<<g_node, blk, 0, stream>>>(csr, offs, N);

    const float* hin = x;
    for (int l = 0; l < 3; ++l) {
        float* hout = (l == 2) ? out : h_tmp;
        node_gemm_kernel<<<g_gemm, blk, 0, stream>>>(hin, Wl + (size_t)l * 4096, bl + l * 64,
                                                     Wr + (size_t)l * 4096, br + l * 64, xl, xr, N);
        edge_score_kernel<<<g_eh, blk, 0, stream>>>(xl, xr, ea, csr,
                                                    We + (size_t)l * 1024, att + l * 64,
                                                    score, E);
        node_pass_kernel<<<g_node, blk, 0, stream>>>(score, xl, csr, offs,
                                                     bias + l * 64, hout, N);
        hin = hout;
    }
}